// Round 10
// baseline (9611.111 us; speedup 1.0000x reference)
//
#include <hip/hip_runtime.h>
#include <hip/hip_bf16.h>

#define BATCH 128
#define SEQ   80
#define EMB   100
#define UNITS 2048
#define EPAD  128   // K-pad for the embedding matmul (100 -> 128)

typedef __attribute__((ext_vector_type(8))) short bf16x8;
typedef __attribute__((ext_vector_type(4))) float f32x4;

static __device__ __forceinline__ short f2bf(float f) {
  __hip_bfloat16 h = __float2bfloat16(f);
  return *reinterpret_cast<short*>(&h);
}
static __device__ __forceinline__ float bf2f(short s) {
  __hip_bfloat16 h = *reinterpret_cast<__hip_bfloat16*>(&s);
  return __bfloat162float(h);
}

// Packed fragment layouts (nch = K/32):
//  A-pack (h state, E): elem(row m, k) at [r=m>>4][kk=k>>5][lane=(m&15)|(((k>>3)&3)<<4)][j=k&7]
//  B-pack (weights):    elem(k, col n) at [c=n>>4][kk=k>>5][lane=(n&15)|(((k>>3)&3)<<4)][j=k&7]
// Both are [..][64 lanes][8] units of 1 KB.

__global__ __launch_bounds__(256) void pack_b_kernel(
    const float* __restrict__ src, int Ksrc, int N, int nch, int totalUnits,
    short* __restrict__ dst) {
  int lane = threadIdx.x & 63;
  int u = blockIdx.x * 4 + (threadIdx.x >> 6);
  if (u >= totalUnits) return;
  int c  = u / nch;
  int kk = u - c * nch;
  int n  = c * 16 + (lane & 15);
  int k0 = kk * 32 + ((lane >> 4) << 3);
  bf16x8 v;
#pragma unroll
  for (int j = 0; j < 8; ++j) {
    int k = k0 + j;
    float f = (k < Ksrc) ? src[k * N + n] : 0.f;
    v[j] = f2bf(f);
  }
  *reinterpret_cast<bf16x8*>(dst + (u * 64 + lane) * 8) = v;
}

__global__ __launch_bounds__(256) void pack_e_kernel(
    const int* __restrict__ tokens, const float* __restrict__ emb,
    short* __restrict__ Ep) {
  int idx = blockIdx.x * 256 + threadIdx.x;   // (t,r,kk,lane)
  if (idx >= SEQ * 8 * 4 * 64) return;
  int lane = idx & 63;
  int kk = (idx >> 6) & 3;
  int r  = (idx >> 8) & 7;
  int t  = idx >> 11;
  int b  = r * 16 + (lane & 15);
  int k0 = kk * 32 + ((lane >> 4) << 3);
  int tok = tokens[b * SEQ + t];
  bf16x8 v;
#pragma unroll
  for (int j = 0; j < 8; ++j) {
    int k = k0 + j;
    v[j] = (k < EMB) ? f2bf(emb[tok * EMB + k]) : (short)0;
  }
  *reinterpret_cast<bf16x8*>(Ep + (size_t)idx * 8) = v;
}

// ---------------------------------------------------------------------------
// Diagonal K-split kernel. Grid 256 = 4 l x 16 cb x 4 ks. Block 512 thr,
// 8 waves (wr2 x wc2 x wk2), output tile 128x128 (full stage M), K-quarter
// per block (1024 for l>=1; E+U0 split for l=0). Last-arriving block of the
// 4 ks reduces partials (fixed order P0+P1+P2+P3 -> deterministic), applies
// bias+tanh, writes h in A-pack layout.
//  - A panels: LDS ring-4 (128 KB), global_load_lds depth-2, ONE barrier/step.
//  - B: registers via asm global_load_dwordx4 (wr-twins dedup in L1), depth-1.
//  - vmcnt: per step issue A(g+2)[4] + B(g+1)[8]; leave newest 12 / 8 / 0.
// ---------------------------------------------------------------------------
#define MFMA(a, b, c) __builtin_amdgcn_mfma_f32_16x16x32_bf16((a), (b), (c), 0, 0, 0)

static __device__ __forceinline__ void gload16(const void* g, void* l) {
  __builtin_amdgcn_global_load_lds(
      (const __attribute__((address_space(1))) void*)g,
      (__attribute__((address_space(3))) void*)l, 16, 0, 0);
}

struct BF { bf16x8 v[4][2]; };   // [ct][q]

#define WAITV(N) asm volatile("s_waitcnt vmcnt(" #N ")" ::: "memory")

__global__ __launch_bounds__(512) void diag_kernel(
    const short* __restrict__ Ep,
    const short* __restrict__ W0p, const short* __restrict__ U0p,
    const short* __restrict__ Wsp, const short* __restrict__ Usp,
    const float* __restrict__ b0, const float* __restrict__ b1,
    short* __restrict__ hbase, float* __restrict__ Pbuf,
    int* __restrict__ cnt, int s) {
  __shared__ char ldsA[4][32768];   // ring-4 of A step-panels (32 KB each)
  __shared__ int s_last;

  const int tid  = threadIdx.x;
  const int lane = tid & 63;
  const int w    = tid >> 6;
  const int wr = w & 1, wc = (w >> 1) & 1, wk = w >> 2;

  // bid -> (xcd, idx); lk = (idx&1)*8 + xcd keeps all 16 cb of one (l,ks)
  // on one XCD (A slice L2-shared); cb = idx>>1.
  int bid = blockIdx.x;
  int xcd = bid & 7, idx = bid >> 3;
  int lk = ((idx & 1) << 3) | xcd;   // 0..15
  int cb = idx >> 1;                 // 0..15
  int l  = lk >> 2, ks = lk & 3;
  int t  = s - l;
  if (t < 0 || t >= SEQ) return;

  const size_t hsz = (size_t)8 * 64 * 64 * 8;
  const int pw = s & 1, pr = pw ^ 1;
  auto hb = [&](int ll, int p) { return hbase + (size_t)(ll * 2 + p) * hsz; };

  // ---- per-block K-range config ----
  const short *Aa = nullptr, *Ba = nullptr, *Ab, *Bb;
  const float* bias;
  int stepsA = 0, stepsB, kqoff;
  if (l == 0) {
    bias = b0;
    if (ks == 0) { stepsA = 1; Aa = Ep + (size_t)t * 16384; Ba = W0p; }
    Ab = hb(0, pr); Bb = U0p; kqoff = ks * 16; stepsB = 4;
  } else {
    bias = b1;
    if (ks < 2) { Ab = hb(l - 1, pr); Bb = Wsp; }
    else        { Ab = hb(l, pr);     Bb = Usp; }
    kqoff = (ks & 1) * 32; stepsB = 8;
  }
  const int total = stepsA + stepsB;

  const size_t lb16 = (size_t)lane * 16;
  char* ldsBase = &ldsA[0][0];

  // stage one 32 KB A panel: thread stages units (r = tid>>6, kq j=0..3)
  auto issueA = [&](int gs) {
    char* dst = ldsBase + ((size_t)(gs & 3) << 15) + ((size_t)(tid >> 6) << 12) + ((tid & 63) << 4);
    const char* src;
    if (gs < stepsA) {
      src = (const char*)Aa + (((size_t)(tid >> 6) * 4) << 10) + ((tid & 63) << 4);
    } else {
      int kq0 = kqoff + (gs - stepsA) * 4;
      src = (const char*)Ab + (((size_t)(tid >> 6) * 64 + kq0) << 10) + ((tid & 63) << 4);
    }
    gload16(src, dst);
    gload16(src + 1024, dst + 1024);
    gload16(src + 2048, dst + 2048);
    gload16(src + 3072, dst + 3072);
  };

  // wave's 8 B fragments for step GS: cols (cb*8 + wc*4 + ct), kq wk*2+{0,1}
#define LOADB(BN, GS)                                                          \
  do {                                                                         \
    const int gs_ = (GS);                                                      \
    const char* base_; size_t nch_; int kq0_;                                  \
    if (gs_ < stepsA) { base_ = (const char*)Ba; nch_ = 4; kq0_ = wk * 2; }    \
    else { base_ = (const char*)Bb; nch_ = 64;                                 \
           kq0_ = kqoff + (gs_ - stepsA) * 4 + wk * 2; }                       \
    _Pragma("unroll")                                                          \
    for (int ct = 0; ct < 4; ++ct) {                                           \
      const char* p_ = base_ + ((((size_t)(cb * 8 + wc * 4 + ct)) * nch_ + kq0_) << 10) + lb16; \
      asm volatile("global_load_dwordx4 %0, %1, off" : "=v"(BN.v[ct][0]) : "v"(p_));        \
      asm volatile("global_load_dwordx4 %0, %1, off" : "=v"(BN.v[ct][1]) : "v"(p_ + 1024)); \
    }                                                                          \
  } while (0)

  f32x4 acc[4][4];
#pragma unroll
  for (int r = 0; r < 4; ++r)
#pragma unroll
    for (int ct = 0; ct < 4; ++ct) acc[r][ct] = (f32x4){0.f, 0.f, 0.f, 0.f};

  auto computeStep = [&](int g, const BF& Bf) {
    const char* base = ldsBase + ((size_t)(g & 3) << 15);
#pragma unroll
    for (int r = 0; r < 4; ++r) {
      bf16x8 a0 = *(const bf16x8*)(base + ((((wr * 4 + r) * 4 + wk * 2 + 0) << 10) + lb16));
      bf16x8 a1 = *(const bf16x8*)(base + ((((wr * 4 + r) * 4 + wk * 2 + 1) << 10) + lb16));
#pragma unroll
      for (int ct = 0; ct < 4; ++ct) {
        acc[r][ct] = MFMA(a0, Bf.v[ct][0], acc[r][ct]);
        acc[r][ct] = MFMA(a1, Bf.v[ct][1], acc[r][ct]);
      }
    }
  };

  // STEP(g): issue A(g+2)[4], B(g+1)[8]; wait leaving newest {A(g+2),B(g+1)}
  // = 12 (forces A(g),A(g+1),B(g)); ONE barrier; compute(g).
  // Ring-4 overwrite distance 3 mod 4 -> race-free with single barrier.
#define STEP(G, BCUR, BNXT)                                          \
  do {                                                               \
    const int g_ = (G);                                              \
    if (g_ + 2 < total) issueA(g_ + 2);                              \
    if (g_ + 1 < total) LOADB(BNXT, g_ + 1);                         \
    if (g_ + 2 < total) { WAITV(12); }                               \
    else if (g_ + 1 < total) { WAITV(8); }                           \
    else { WAITV(0); }                                               \
    __builtin_amdgcn_s_barrier();                                    \
    __builtin_amdgcn_sched_barrier(0);                               \
    computeStep(g_, BCUR);                                           \
    __builtin_amdgcn_sched_barrier(0);                               \
  } while (0)

  BF Bq0, Bq1;
  issueA(0); issueA(1);
  LOADB(Bq0, 0);

  for (int g = 0; g < total; g += 2) {
    STEP(g, Bq0, Bq1);
    if (g + 1 < total) STEP(g + 1, Bq1, Bq0);
  }
#undef STEP
#undef LOADB

  // ---- intra-block wk reduction (wk=1 -> wk=0) via LDS slots 0-1 ----
  const int wid = wr * 2 + wc;
  __syncthreads();
  if (wk == 1) {
#pragma unroll
    for (int r = 0; r < 4; ++r)
#pragma unroll
      for (int ct = 0; ct < 4; ++ct)
        *(f32x4*)(ldsBase + ((((size_t)(wid * 16 + r * 4 + ct)) * 64 + lane) << 4)) = acc[r][ct];
  }
  __syncthreads();
  if (wk == 0) {
#pragma unroll
    for (int r = 0; r < 4; ++r)
#pragma unroll
      for (int ct = 0; ct < 4; ++ct)
        acc[r][ct] += *(const f32x4*)(ldsBase + ((((size_t)(wid * 16 + r * 4 + ct)) * 64 + lane) << 4));
  }

  // ---- store partial, count, last block reduces ----
  const int tileIdx = l * 16 + cb;
  float* Pq = Pbuf + (((size_t)tileIdx * 4 + ks) << 14);   // 16384 floats
  if (wk == 0) {
#pragma unroll
    for (int r = 0; r < 4; ++r)
#pragma unroll
      for (int ct = 0; ct < 4; ++ct)
        *(f32x4*)(Pq + ((((size_t)(wid * 16 + r * 4 + ct)) * 64 + lane) << 2)) = acc[r][ct];
  }
  __threadfence();            // release: make partials visible device-wide
  __syncthreads();
  if (tid == 0) s_last = (atomicAdd(&cnt[s * 64 + tileIdx], 1) == 3);
  __syncthreads();
  if (!s_last) return;
  __threadfence();            // acquire: see other blocks' partials

  if (wk == 0) {
    // fixed-order sum P0+P1+P2+P3 (deterministic regardless of reducer id)
    f32x4 sum[4][4];
    const float* P0 = Pbuf + (((size_t)tileIdx * 4 + 0) << 14);
#pragma unroll
    for (int r = 0; r < 4; ++r)
#pragma unroll
      for (int ct = 0; ct < 4; ++ct)
        sum[r][ct] = *(const f32x4*)(P0 + ((((size_t)(wid * 16 + r * 4 + ct)) * 64 + lane) << 2));
#pragma unroll
    for (int ko = 1; ko < 4; ++ko) {
      const float* Pk = Pbuf + (((size_t)tileIdx * 4 + ko) << 14);
#pragma unroll
      for (int r = 0; r < 4; ++r)
#pragma unroll
        for (int ct = 0; ct < 4; ++ct)
          sum[r][ct] += *(const f32x4*)(Pk + ((((size_t)(wid * 16 + r * 4 + ct)) * 64 + lane) << 2));
    }
    // epilogue: bias + tanh -> h (A-pack layout), parity pw
    short* H = hb(l, pw);
    const int lo = lane & 15, hi = lane >> 4;
    const int nb = cb * 128 + wc * 64;
    float bvv[4] = {bias[nb + lo], bias[nb + 16 + lo], bias[nb + 32 + lo], bias[nb + 48 + lo]};
#pragma unroll
    for (int r = 0; r < 4; ++r)
#pragma unroll
      for (int ct = 0; ct < 4; ++ct) {
#pragma unroll
        for (int i = 0; i < 4; ++i) {
          int m = wr * 64 + r * 16 + hi * 4 + i;
          int n = nb + ct * 16 + lo;
          float z = sum[r][ct][i] + bvv[ct];
          float e = __expf(2.f * z);
          float th = 1.f - 2.f / (e + 1.f);
          int rr = m >> 4, kk = n >> 5;
          int lp = (m & 15) | (((n >> 3) & 3) << 4);
          H[(((size_t)rr * 64 + kk) * 64 + lp) * 8 + (n & 7)] = f2bf(th);
        }
      }
  }
}

// ---------------------------------------------------------------------------
// Output head: out[b] = sigmoid(h3[b] . Wo + bo); h3 in A-pack layout.
// ---------------------------------------------------------------------------
__global__ __launch_bounds__(256) void head_kernel(
    const short* __restrict__ h3, const float* __restrict__ Wo,
    const float* __restrict__ bo, float* __restrict__ out) {
  __shared__ float sred[4];
  int b = blockIdx.x, tid = threadIdx.x;
  int kk = tid >> 2, hi = tid & 3;
  const bf16x8 v = *reinterpret_cast<const bf16x8*>(
      h3 + (((size_t)(b >> 4) * 64 + kk) * 64 + ((b & 15) | (hi << 4))) * 8);
  int k0 = kk * 32 + hi * 8;
  float acc = 0.f;
#pragma unroll
  for (int j = 0; j < 8; ++j) acc += bf2f(v[j]) * Wo[k0 + j];
  for (int off = 32; off > 0; off >>= 1) acc += __shfl_down(acc, off);
  if ((tid & 63) == 0) sred[tid >> 6] = acc;
  __syncthreads();
  if (tid == 0) {
    float z = sred[0] + sred[1] + sred[2] + sred[3] + bo[0];
    out[b] = 1.f / (1.f + expf(-z));
  }
}

extern "C" void kernel_launch(void* const* d_in, const int* in_sizes, int n_in,
                              void* d_out, int out_size, void* d_ws, size_t ws_size,
                              hipStream_t stream) {
  const int*   tokens = (const int*)d_in[0];
  const float* emb    = (const float*)d_in[1];
  const float* W0     = (const float*)d_in[2];
  const float* U0     = (const float*)d_in[3];
  const float* b0     = (const float*)d_in[4];
  const float* W1     = (const float*)d_in[5];
  const float* U1     = (const float*)d_in[6];
  const float* b1     = (const float*)d_in[7];
  const float* Wo     = (const float*)d_in[8];
  const float* bo     = (const float*)d_in[9];
  float* out = (float*)d_out;
  char*  ws  = (char*)d_ws;

  // byte offsets
  const size_t W0P_OFF = 0;                       // 512 KB
  const size_t U0P_OFF = W0P_OFF + (size_t)524288;
  const size_t W1P_OFF = U0P_OFF + (size_t)8388608;
  const size_t U1P_OFF = W1P_OFF + (size_t)8388608;
  const size_t EP_OFF  = U1P_OFF + (size_t)8388608;   // 2.5 MB
  const size_t H_OFF   = EP_OFF + (size_t)2621440;    // 4 MB (8 bufs x 512 KB)
  const size_t P_OFF   = H_OFF + (size_t)4194304;     // 16 MB partials
  const size_t C_OFF   = P_OFF + (size_t)16777216;    // counters

  short* W0p = (short*)(ws + W0P_OFF);
  short* U0p = (short*)(ws + U0P_OFF);
  short* W1p = (short*)(ws + W1P_OFF);
  short* U1p = (short*)(ws + U1P_OFF);
  short* Ep  = (short*)(ws + EP_OFF);
  short* hbase = (short*)(ws + H_OFF);
  float* Pbuf  = (float*)(ws + P_OFF);
  int*   cnt   = (int*)(ws + C_OFF);
  const size_t H_SZ = (size_t)8 * 64 * 64 * 8;   // shorts per h buffer

  {
    int unitsW0 = (UNITS / 16) * (EPAD / 32);   // 512
    pack_b_kernel<<<(unitsW0 + 3) / 4, 256, 0, stream>>>(W0, EMB, UNITS, EPAD / 32, unitsW0, W0p);
    int unitsU = (UNITS / 16) * (UNITS / 32);   // 8192
    pack_b_kernel<<<(unitsU + 3) / 4, 256, 0, stream>>>(U0, UNITS, UNITS, UNITS / 32, unitsU, U0p);
    pack_b_kernel<<<(unitsU + 3) / 4, 256, 0, stream>>>(W1, UNITS, UNITS, UNITS / 32, unitsU, W1p);
    pack_b_kernel<<<(unitsU + 3) / 4, 256, 0, stream>>>(U1, UNITS, UNITS, UNITS / 32, unitsU, U1p);
    int ne = SEQ * 8 * 4 * 64;
    pack_e_kernel<<<(ne + 255) / 256, 256, 0, stream>>>(tokens, emb, Ep);
  }

  // zero h double-buffers (h_l[-1] = 0) and per-diagonal tile counters
  hipMemsetAsync(hbase, 0, 8u * 262144u * 2u, stream);
  hipMemsetAsync(cnt, 0, (size_t)83 * 64 * 4, stream);

  // ---- 83 diagonals: s = t + l ----
  for (int s = 0; s <= SEQ - 1 + 3; ++s) {
    diag_kernel<<<256, 512, 0, stream>>>(Ep, W0p, U0p, W1p, U1p, b0, b1,
                                         hbase, Pbuf, cnt, s);
  }

  // final head: h3[SEQ-1] written at diagonal 82 (parity 0)
  head_kernel<<<BATCH, 256, 0, stream>>>(hbase + 6 * H_SZ, Wo, bo, out);
}

// Round 11
// 1489.182 us; speedup vs baseline: 6.4540x; 6.4540x over previous
//
#include <hip/hip_runtime.h>
#include <hip/hip_bf16.h>

#define BATCH 128
#define SEQ   80
#define EMB   100
#define UNITS 2048
#define EPAD  128   // K-pad for the embedding matmul (100 -> 128)

typedef __attribute__((ext_vector_type(8))) short bf16x8;
typedef __attribute__((ext_vector_type(4))) float f32x4;

static __device__ __forceinline__ short f2bf(float f) {
  __hip_bfloat16 h = __float2bfloat16(f);
  return *reinterpret_cast<short*>(&h);
}
static __device__ __forceinline__ float bf2f(short s) {
  __hip_bfloat16 h = *reinterpret_cast<__hip_bfloat16*>(&s);
  return __bfloat162float(h);
}

// Packed fragment layouts (nch = K/32):
//  A-pack (h state, E): elem(row m, k) at [r=m>>4][kk=k>>5][lane=(m&15)|(((k>>3)&3)<<4)][j=k&7]
//  B-pack (weights):    elem(k, col n) at [c=n>>4][kk=k>>5][lane=(n&15)|(((k>>3)&3)<<4)][j=k&7]
// Both are [..][64 lanes][8] units of 1 KB.

__global__ __launch_bounds__(256) void pack_b_kernel(
    const float* __restrict__ src, int Ksrc, int N, int nch, int totalUnits,
    short* __restrict__ dst) {
  int lane = threadIdx.x & 63;
  int u = blockIdx.x * 4 + (threadIdx.x >> 6);
  if (u >= totalUnits) return;
  int c  = u / nch;
  int kk = u - c * nch;
  int n  = c * 16 + (lane & 15);
  int k0 = kk * 32 + ((lane >> 4) << 3);
  bf16x8 v;
#pragma unroll
  for (int j = 0; j < 8; ++j) {
    int k = k0 + j;
    float f = (k < Ksrc) ? src[k * N + n] : 0.f;
    v[j] = f2bf(f);
  }
  *reinterpret_cast<bf16x8*>(dst + (u * 64 + lane) * 8) = v;
}

__global__ __launch_bounds__(256) void pack_e_kernel(
    const int* __restrict__ tokens, const float* __restrict__ emb,
    short* __restrict__ Ep) {
  int idx = blockIdx.x * 256 + threadIdx.x;   // (t,r,kk,lane)
  if (idx >= SEQ * 8 * 4 * 64) return;
  int lane = idx & 63;
  int kk = (idx >> 6) & 3;
  int r  = (idx >> 8) & 7;
  int t  = idx >> 11;
  int b  = r * 16 + (lane & 15);
  int k0 = kk * 32 + ((lane >> 4) << 3);
  int tok = tokens[b * SEQ + t];
  bf16x8 v;
#pragma unroll
  for (int j = 0; j < 8; ++j) {
    int k = k0 + j;
    v[j] = (k < EMB) ? f2bf(emb[tok * EMB + k]) : (short)0;
  }
  *reinterpret_cast<bf16x8*>(Ep + (size_t)idx * 8) = v;
}

// ---------------------------------------------------------------------------
// Diagonal-wavefront GEMM stage, K-split-4, 16-wave (1024 thr) structure.
//  - Waves: wr=w&1 (rows), wc=(w>>1)&1 (cols), wk=w>>2 (kq of the step).
//  - A panels: LDS ring-4 (64 KB), global_load_lds depth-2, ONE barrier/step.
//    Each wave stages exactly one 1 KB unit/step (1 gload_lds instr/wave).
//  - B: registers, asm global_load_dwordx4 x2/wave/step (wr-twins L1-dedup).
//  - Issue order B then A. vmcnt ledger per wave (oldest->newest), entering
//    STEP(g) for g>=1: [A(g),B(g)a,B(g)b,A(g+1)]; issue B(g+1)ab,A(g+2) -> 7;
//    need A(g)+B(g) done -> leave newest 4 = {A(g+1),B(g+1)ab,A(g+2)}.
//    g=0: [A0,A1,B0ab] + issue B1ab,A2 -> leave 3. total-2 -> 3, total-1 -> 0.
//  - End: wk=1..3 partials reduced into wk=0 via LDS in FIXED order.
// Block = 64x64 tile; 4 MFMA per wave per step; 4 waves/SIMD occupancy.
// ---------------------------------------------------------------------------
#define MFMA(a, b, c) __builtin_amdgcn_mfma_f32_16x16x32_bf16((a), (b), (c), 0, 0, 0)

static __device__ __forceinline__ void gload16(const void* g, void* l) {
  __builtin_amdgcn_global_load_lds(
      (const __attribute__((address_space(1))) void*)g,
      (__attribute__((address_space(3))) void*)l, 16, 0, 0);
}

struct BF { bf16x8 v[2]; };   // [y]

#define WAITV(N) asm volatile("s_waitcnt vmcnt(" #N ")" ::: "memory")

__global__ __launch_bounds__(1024) void diag_kernel(
    const short* __restrict__ Ep,
    const short* __restrict__ W0p, const short* __restrict__ U0p,
    const short* __restrict__ Wsp, const short* __restrict__ Usp,
    const float* __restrict__ b0, const float* __restrict__ b1,
    short* __restrict__ hbase, int s) {
  __shared__ char ldsA[4][16384];   // ring-4 of A step-panels (16 KB each)

  const int tid  = threadIdx.x;
  const int lane = tid & 63;
  const int w    = tid >> 6;
  const int wr = w & 1, wc = (w >> 1) & 1, wk = w >> 2;

  // XCD-affine mapping: xcd = bid & 7 owns 4 consecutive cb's x all rb's
  int bid = blockIdx.x;
  int xcd = bid & 7, idx = bid >> 3;
  int cb  = xcd * 4 + (idx & 3);   // 0..31
  int rb  = idx >> 2;              // 0..7
  int l   = rb >> 1;
  int t   = s - l;
  if (t < 0 || t >= SEQ) return;

  const size_t hsz = (size_t)8 * 64 * 64 * 8;
  const int pw = s & 1, pr = pw ^ 1;
  auto hb = [&](int ll, int p) { return hbase + (size_t)(ll * 2 + p) * hsz; };

  const short *A1, *B1, *A2, *B2;
  const float* bias;
  int steps0, nch1;
  if (l == 0) {
    A1 = Ep + (size_t)t * 16384; B1 = W0p; steps0 = 1;  nch1 = 4;
    A2 = hb(0, pr); B2 = U0p; bias = b0;
  } else {
    A1 = hb(l - 1, pr); B1 = Wsp; steps0 = 16; nch1 = 64;
    A2 = hb(l, pr);     B2 = Usp; bias = b1;
  }
  const int rloc0 = (rb & 1) * 4;    // layer-local r-tile base
  const int ct0   = cb * 4;          // global c-tile base
  const int total = steps0 + 16;

  // ---- A staging: unit u = tid>>6 -> (rt = u>>2, kq = u&3); 1 load/thread ----
  const int uA = tid >> 6;
  const int rtA = uA >> 2, kqA = uA & 3;
  const size_t lb16 = (size_t)lane * 16;
  const char* a1T = (const char*)A1 + (((size_t)(rloc0 + rtA) * nch1 + kqA) << 10) + lb16;
  const char* a2T = (const char*)A2 + (((size_t)(rloc0 + rtA) * 64 + kqA) << 10) + lb16;
  char* ldsA0 = &ldsA[0][0] + (size_t)tid * 16;

  auto issueA = [&](int gs) {
    char* dst = ldsA0 + (size_t)(gs & 3) * 16384;
    const char* src;
    if (gs < steps0) src = a1T + (size_t)gs * 4096;
    else             src = a2T + (size_t)(gs - steps0) * 4096;
    gload16(src, dst);
  };

  // ---- B register path: wave's 2 cols (ct0 + wc*2 + {0,1}), kq = wk ----
  const char* b1T0 = (const char*)B1 + (((size_t)(ct0 + wc * 2 + 0) * nch1 + wk) << 10) + lb16;
  const char* b1T1 = (const char*)B1 + (((size_t)(ct0 + wc * 2 + 1) * nch1 + wk) << 10) + lb16;
  const char* b2T0 = (const char*)B2 + (((size_t)(ct0 + wc * 2 + 0) * 64 + wk) << 10) + lb16;
  const char* b2T1 = (const char*)B2 + (((size_t)(ct0 + wc * 2 + 1) * 64 + wk) << 10) + lb16;

#define LOADB(BN, GS)                                                         \
  do {                                                                        \
    const int gs_ = (GS);                                                     \
    const char *p0_, *p1_;                                                    \
    if (gs_ < steps0) {                                                       \
      size_t o_ = (size_t)gs_ * 4096;                                         \
      p0_ = b1T0 + o_; p1_ = b1T1 + o_;                                       \
    } else {                                                                  \
      size_t o_ = (size_t)(gs_ - steps0) * 4096;                              \
      p0_ = b2T0 + o_; p1_ = b2T1 + o_;                                       \
    }                                                                         \
    asm volatile("global_load_dwordx4 %0, %1, off" : "=v"(BN.v[0]) : "v"(p0_)); \
    asm volatile("global_load_dwordx4 %0, %1, off" : "=v"(BN.v[1]) : "v"(p1_)); \
  } while (0)

  f32x4 acc[2][2];
#pragma unroll
  for (int x = 0; x < 2; ++x)
#pragma unroll
    for (int y = 0; y < 2; ++y) acc[x][y] = (f32x4){0.f, 0.f, 0.f, 0.f};

  auto computeStep = [&](int g, const BF& Bf) {
    const char* base = &ldsA[g & 3][0];
#pragma unroll
    for (int x = 0; x < 2; ++x) {
      bf16x8 av = *(const bf16x8*)(base + ((((wr * 2 + x) * 4 + wk) << 10) + lb16));
#pragma unroll
      for (int y = 0; y < 2; ++y)
        acc[x][y] = MFMA(av, Bf.v[y], acc[x][y]);
    }
  };

  // STEP(g): issue B(g+1) then A(g+2); counted wait (ledger in header);
  // ONE barrier; compute(g). Ring-4 overwrite distance 3 mod 4 -> race-free.
#define STEP(G, BCUR, BNXT)                                          \
  do {                                                               \
    const int g_ = (G);                                              \
    if (g_ + 1 < total) LOADB(BNXT, g_ + 1);                         \
    __builtin_amdgcn_sched_barrier(0);                               \
    if (g_ + 2 < total) issueA(g_ + 2);                              \
    if (g_ == 0) { WAITV(3); }                                       \
    else if (g_ + 2 < total) { WAITV(4); }                           \
    else if (g_ + 1 < total) { WAITV(3); }                           \
    else { WAITV(0); }                                               \
    __builtin_amdgcn_s_barrier();                                    \
    __builtin_amdgcn_sched_barrier(0);                               \
    computeStep(g_, BCUR);                                           \
    __builtin_amdgcn_sched_barrier(0);                               \
  } while (0)

  BF Bq0, Bq1;
  issueA(0); issueA(1);
  LOADB(Bq0, 0);

  for (int g = 0; g < total; g += 2) {
    STEP(g, Bq0, Bq1);
    if (g + 1 < total) STEP(g + 1, Bq1, Bq0);
  }
#undef STEP
#undef LOADB

  // ---- K-split reduction: wk=1..3 -> LDS -> wk=0, fixed order ----
  const int wid = wr * 2 + wc;   // 0..3
  __syncthreads();
  if (wk != 0) {
    char* dst = &ldsA[0][0] + ((size_t)((wk - 1) * 4 + wid) << 12);
#pragma unroll
    for (int x = 0; x < 2; ++x)
#pragma unroll
      for (int y = 0; y < 2; ++y)
        *(f32x4*)(dst + ((((x * 2 + y) * 64) + lane) << 4)) = acc[x][y];
  }
  __syncthreads();
  if (wk != 0) return;
#pragma unroll
  for (int kq = 1; kq < 4; ++kq) {
    const char* srcp = &ldsA[0][0] + ((size_t)((kq - 1) * 4 + wid) << 12);
#pragma unroll
    for (int x = 0; x < 2; ++x)
#pragma unroll
      for (int y = 0; y < 2; ++y)
        acc[x][y] += *(const f32x4*)(srcp + ((((x * 2 + y) * 64) + lane) << 4));
  }

  // Epilogue: bias + tanh, store into A-pack layout of h_l (parity pw).
  // C/D layout: col = lane&15, row = (lane>>4)*4 + i.
  short* H = hb(l, pw);
  const int lo = lane & 15, hi = lane >> 4;
  const int mb = (rb & 1) * 64 + wr * 32;
  const int nb = cb * 64 + wc * 32;
  const float bv0 = bias[nb + lo];
  const float bv1 = bias[nb + 16 + lo];
#pragma unroll
  for (int x = 0; x < 2; ++x)
#pragma unroll
    for (int y = 0; y < 2; ++y) {
      float bbv = y ? bv1 : bv0;
#pragma unroll
      for (int i = 0; i < 4; ++i) {
        int m = mb + x * 16 + hi * 4 + i;
        int n = nb + y * 16 + lo;
        float z = acc[x][y][i] + bbv;
        float e = __expf(2.f * z);
        float th = 1.f - 2.f / (e + 1.f);
        int r  = m >> 4, kk = n >> 5;
        int lp = (m & 15) | (((n >> 3) & 3) << 4);
        H[(((size_t)r * 64 + kk) * 64 + lp) * 8 + (n & 7)] = f2bf(th);
      }
    }
}

// ---------------------------------------------------------------------------
// Output head: out[b] = sigmoid(h3[b] . Wo + bo); h3 in A-pack layout.
// ---------------------------------------------------------------------------
__global__ __launch_bounds__(256) void head_kernel(
    const short* __restrict__ h3, const float* __restrict__ Wo,
    const float* __restrict__ bo, float* __restrict__ out) {
  __shared__ float sred[4];
  int b = blockIdx.x, tid = threadIdx.x;
  int kk = tid >> 2, hi = tid & 3;
  const bf16x8 v = *reinterpret_cast<const bf16x8*>(
      h3 + (((size_t)(b >> 4) * 64 + kk) * 64 + ((b & 15) | (hi << 4))) * 8);
  int k0 = kk * 32 + hi * 8;
  float acc = 0.f;
#pragma unroll
  for (int j = 0; j < 8; ++j) acc += bf2f(v[j]) * Wo[k0 + j];
  for (int off = 32; off > 0; off >>= 1) acc += __shfl_down(acc, off);
  if ((tid & 63) == 0) sred[tid >> 6] = acc;
  __syncthreads();
  if (tid == 0) {
    float z = sred[0] + sred[1] + sred[2] + sred[3] + bo[0];
    out[b] = 1.f / (1.f + expf(-z));
  }
}

extern "C" void kernel_launch(void* const* d_in, const int* in_sizes, int n_in,
                              void* d_out, int out_size, void* d_ws, size_t ws_size,
                              hipStream_t stream) {
  const int*   tokens = (const int*)d_in[0];
  const float* emb    = (const float*)d_in[1];
  const float* W0     = (const float*)d_in[2];
  const float* U0     = (const float*)d_in[3];
  const float* b0     = (const float*)d_in[4];
  const float* W1     = (const float*)d_in[5];
  const float* U1     = (const float*)d_in[6];
  const float* b1     = (const float*)d_in[7];
  const float* Wo     = (const float*)d_in[8];
  const float* bo     = (const float*)d_in[9];
  float* out = (float*)d_out;
  short* ws  = (short*)d_ws;

  const size_t W0P_SZ = (size_t)128 * 4 * 512;     // 262144
  const size_t UP_SZ  = (size_t)128 * 64 * 512;    // 4194304
  const size_t EP_SZ  = (size_t)SEQ * 16384;       // 1310720
  const size_t H_SZ   = (size_t)8 * 64 * 64 * 8;   // 262144 per buffer

  short* W0p = ws;
  short* U0p = W0p + W0P_SZ;
  short* W1p = U0p + UP_SZ;
  short* U1p = W1p + UP_SZ;
  short* Ep  = U1p + UP_SZ;
  short* hbase = Ep + EP_SZ;

  {
    int unitsW0 = (UNITS / 16) * (EPAD / 32);   // 512
    pack_b_kernel<<<(unitsW0 + 3) / 4, 256, 0, stream>>>(W0, EMB, UNITS, EPAD / 32, unitsW0, W0p);
    int unitsU = (UNITS / 16) * (UNITS / 32);   // 8192
    pack_b_kernel<<<(unitsU + 3) / 4, 256, 0, stream>>>(U0, UNITS, UNITS, UNITS / 32, unitsU, U0p);
    pack_b_kernel<<<(unitsU + 3) / 4, 256, 0, stream>>>(W1, UNITS, UNITS, UNITS / 32, unitsU, W1p);
    pack_b_kernel<<<(unitsU + 3) / 4, 256, 0, stream>>>(U1, UNITS, UNITS, UNITS / 32, unitsU, U1p);
    int ne = SEQ * 8 * 4 * 64;
    pack_e_kernel<<<(ne + 255) / 256, 256, 0, stream>>>(tokens, emb, Ep);
  }

  // zero all 8 h double-buffers (provides h_l[-1] = 0)
  hipMemsetAsync(hbase, 0, 8u * H_SZ * 2u, stream);

  // ---- 83 diagonals: s = t + l ----
  for (int s = 0; s <= SEQ - 1 + 3; ++s) {
    diag_kernel<<<256, 1024, 0, stream>>>(Ep, W0p, U0p, W1p, U1p, b0, b1, hbase, s);
  }

  // final head: h3[SEQ-1] written at diagonal 82 (parity 0)
  head_kernel<<<BATCH, 256, 0, stream>>>(hbase + 6 * H_SZ, Wo, bo, out);
}

// Round 12
// 1335.658 us; speedup vs baseline: 7.1958x; 1.1149x over previous
//
#include <hip/hip_runtime.h>
#include <hip/hip_bf16.h>

#define BATCH 128
#define SEQ   80
#define EMB   100
#define UNITS 2048
#define EPAD  128   // K-pad for the embedding matmul (100 -> 128)

typedef __attribute__((ext_vector_type(8))) short bf16x8;
typedef __attribute__((ext_vector_type(4))) float f32x4;

static __device__ __forceinline__ short f2bf(float f) {
  __hip_bfloat16 h = __float2bfloat16(f);
  return *reinterpret_cast<short*>(&h);
}
static __device__ __forceinline__ float bf2f(short s) {
  __hip_bfloat16 h = *reinterpret_cast<__hip_bfloat16*>(&s);
  return __bfloat162float(h);
}

// Packed fragment layouts (nch = K/32):
//  A-pack (h state, E): elem(row m, k) at [r=m>>4][kk=k>>5][lane=(m&15)|(((k>>3)&3)<<4)][j=k&7]
//  B-pack (weights):    elem(k, col n) at [c=n>>4][kk=k>>5][lane=(n&15)|(((k>>3)&3)<<4)][j=k&7]
// Both are [..][64 lanes][8] units of 1 KB.

__global__ __launch_bounds__(256) void pack_b_kernel(
    const float* __restrict__ src, int Ksrc, int N, int nch, int totalUnits,
    short* __restrict__ dst) {
  int lane = threadIdx.x & 63;
  int u = blockIdx.x * 4 + (threadIdx.x >> 6);
  if (u >= totalUnits) return;
  int c  = u / nch;
  int kk = u - c * nch;
  int n  = c * 16 + (lane & 15);
  int k0 = kk * 32 + ((lane >> 4) << 3);
  bf16x8 v;
#pragma unroll
  for (int j = 0; j < 8; ++j) {
    int k = k0 + j;
    float f = (k < Ksrc) ? src[k * N + n] : 0.f;
    v[j] = f2bf(f);
  }
  *reinterpret_cast<bf16x8*>(dst + (u * 64 + lane) * 8) = v;
}

__global__ __launch_bounds__(256) void pack_e_kernel(
    const int* __restrict__ tokens, const float* __restrict__ emb,
    short* __restrict__ Ep) {
  int idx = blockIdx.x * 256 + threadIdx.x;   // (t,r,kk,lane)
  if (idx >= SEQ * 8 * 4 * 64) return;
  int lane = idx & 63;
  int kk = (idx >> 6) & 3;
  int r  = (idx >> 8) & 7;
  int t  = idx >> 11;
  int b  = r * 16 + (lane & 15);
  int k0 = kk * 32 + ((lane >> 4) << 3);
  int tok = tokens[b * SEQ + t];
  bf16x8 v;
#pragma unroll
  for (int j = 0; j < 8; ++j) {
    int k = k0 + j;
    v[j] = (k < EMB) ? f2bf(emb[tok * EMB + k]) : (short)0;
  }
  *reinterpret_cast<bf16x8*>(Ep + (size_t)idx * 8) = v;
}

// ---------------------------------------------------------------------------
// Diagonal-wavefront GEMM stage. 1024 threads = 16 waves (wr2 x wc2 x wk4).
// Block = 64x64 output tile.
//  l==0 path: BK=128, 17 steps (1 E-step + 16 U0-steps), ring-4 x 16 KB.
//  l>=1 path: BK=256, 16 steps (8 W + 8 U), ring-4 x 32 KB (128 KB LDS).
//  A panels staged via global_load_lds; B in registers via asm dwordx4
//  (wr-twin waves issue identical B addresses -> L1 dedup). ONE s_barrier
//  per step; exact counted vmcnt (ledger in comments); never drains mid-loop.
//  K-split partials (wk=1..3) reduced into wk=0 via LDS in FIXED order.
// ---------------------------------------------------------------------------
#define MFMA(a, b, c) __builtin_amdgcn_mfma_f32_16x16x32_bf16((a), (b), (c), 0, 0, 0)

static __device__ __forceinline__ void gload16(const void* g, void* l) {
  __builtin_amdgcn_global_load_lds(
      (const __attribute__((address_space(1))) void*)g,
      (__attribute__((address_space(3))) void*)l, 16, 0, 0);
}

struct BF1 { bf16x8 v[2]; };        // l==0: [y]
struct BF2 { bf16x8 v[2][2]; };     // l>=1: [y][q]

#define WAITV(N) asm volatile("s_waitcnt vmcnt(" #N ")" ::: "memory")

__global__ __launch_bounds__(1024) void diag_kernel(
    const short* __restrict__ Ep,
    const short* __restrict__ W0p, const short* __restrict__ U0p,
    const short* __restrict__ Wsp, const short* __restrict__ Usp,
    const float* __restrict__ b0, const float* __restrict__ b1,
    short* __restrict__ hbase, int s) {
  __shared__ char ldsA[131072];   // l>=1: ring-4 x 32 KB; l==0: ring-4 x 16 KB

  const int tid  = threadIdx.x;
  const int lane = tid & 63;
  const int w    = tid >> 6;
  const int wr = w & 1, wc = (w >> 1) & 1, wk = w >> 2;

  // XCD-affine mapping: xcd = bid & 7 owns 4 consecutive cb's x all rb's
  int bid = blockIdx.x;
  int xcd = bid & 7, idx = bid >> 3;
  int cb  = xcd * 4 + (idx & 3);   // 0..31
  int rb  = idx >> 2;              // 0..7
  int l   = rb >> 1;
  int t   = s - l;
  if (t < 0 || t >= SEQ) return;

  const size_t hsz = (size_t)8 * 64 * 64 * 8;
  const int pw = s & 1, pr = pw ^ 1;
  auto hb = [&](int ll, int p) { return hbase + (size_t)(ll * 2 + p) * hsz; };

  const int rloc0 = (rb & 1) * 4;    // layer-local r-tile base
  const int ct0   = cb * 4;          // global c-tile base
  const size_t lb16 = (size_t)lane * 16;
  const int uA = tid >> 6;           // staging unit id, 0..15
  char* lds = &ldsA[0];

  f32x4 acc[2][2];
#pragma unroll
  for (int x = 0; x < 2; ++x)
#pragma unroll
    for (int y = 0; y < 2; ++y) acc[x][y] = (f32x4){0.f, 0.f, 0.f, 0.f};

  if (l == 0) {
    // ===================== BK=128 path: 1 E-step + 16 U0-steps ==============
    const short* A1 = Ep + (size_t)t * 16384;
    const short* A2 = hb(0, pr);
    const int total = 17;
    // A staging: unit uA -> (rt = uA>>2, kq = uA&3); 1 gload16/thread/step
    const char* a1T = (const char*)A1 + (((size_t)(rloc0 + (uA >> 2)) * 4 + (uA & 3)) << 10) + lb16;
    const char* a2T = (const char*)A2 + (((size_t)(rloc0 + (uA >> 2)) * 64 + (uA & 3)) << 10) + lb16;
    char* dstT = lds + (size_t)tid * 16;

    auto issueA = [&](int gs) {
      char* dst = dstT + (size_t)(gs & 3) * 16384;
      const char* src = (gs == 0) ? a1T : a2T + (size_t)(gs - 1) * 4096;
      gload16(src, dst);
    };
    // B: wave's 2 cols, kq = wk
    const char* bw0 = (const char*)W0p + (((size_t)(ct0 + wc * 2 + 0) * 4 + wk) << 10) + lb16;
    const char* bw1 = (const char*)W0p + (((size_t)(ct0 + wc * 2 + 1) * 4 + wk) << 10) + lb16;
    const char* bu0 = (const char*)U0p + (((size_t)(ct0 + wc * 2 + 0) * 64 + wk) << 10) + lb16;
    const char* bu1 = (const char*)U0p + (((size_t)(ct0 + wc * 2 + 1) * 64 + wk) << 10) + lb16;

#define LOADB0(BN, GS)                                                        \
  do {                                                                        \
    const int gs_ = (GS);                                                     \
    const char *p0_, *p1_;                                                    \
    if (gs_ == 0) { p0_ = bw0; p1_ = bw1; }                                   \
    else { size_t o_ = (size_t)(gs_ - 1) * 4096; p0_ = bu0 + o_; p1_ = bu1 + o_; } \
    asm volatile("global_load_dwordx4 %0, %1, off" : "=v"(BN.v[0]) : "v"(p0_)); \
    asm volatile("global_load_dwordx4 %0, %1, off" : "=v"(BN.v[1]) : "v"(p1_)); \
  } while (0)

    auto computeStep = [&](int g, const BF1& Bf) {
      const char* base = lds + (size_t)(g & 3) * 16384;
#pragma unroll
      for (int x = 0; x < 2; ++x) {
        bf16x8 av = *(const bf16x8*)(base + ((((wr * 2 + x) * 4 + wk) << 10) + lb16));
#pragma unroll
        for (int y = 0; y < 2; ++y)
          acc[x][y] = MFMA(av, Bf.v[y], acc[x][y]);
      }
    };

    // ledger (per thread): prologue A0(1),B0(2),A1(1). STEP(g): issue
    // B(g+1)(2), A(g+2)(1) -> 7 outstanding; leave newest 4 = {A(g+1),B(g+1),A(g+2)}.
    // g=total-2: leave 3 = {A(g+1),B(g+1)}; g=total-1: 0.
#define STEP0(G, BCUR, BNXT)                                         \
  do {                                                               \
    const int g_ = (G);                                              \
    if (g_ + 1 < total) LOADB0(BNXT, g_ + 1);                        \
    if (g_ + 2 < total) issueA(g_ + 2);                              \
    if (g_ + 2 < total) { WAITV(4); }                                \
    else if (g_ + 1 < total) { WAITV(3); }                           \
    else { WAITV(0); }                                               \
    __builtin_amdgcn_s_barrier();                                    \
    __builtin_amdgcn_sched_barrier(0);                               \
    computeStep(g_, BCUR);                                           \
    __builtin_amdgcn_sched_barrier(0);                               \
  } while (0)

    BF1 Bq0, Bq1;
    issueA(0); LOADB0(Bq0, 0); issueA(1);
    for (int g = 0; g < total; g += 2) {
      STEP0(g, Bq0, Bq1);
      if (g + 1 < total) STEP0(g + 1, Bq1, Bq0);
    }
#undef STEP0
#undef LOADB0
  } else {
    // ===================== BK=256 path: 8 W-steps + 8 U-steps ===============
    const short* Aw = hb(l - 1, pr);
    const short* Au = hb(l, pr);
    // A staging: units uA (rt=uA>>3, kq=uA&7) and uA+16 (rt+2); 2 loads/thread
    const int rtl = uA >> 3, kql = uA & 7;
    const char* awT = (const char*)Aw + (((size_t)(rloc0 + rtl) * 64 + kql) << 10) + lb16;
    const char* auT = (const char*)Au + (((size_t)(rloc0 + rtl) * 64 + kql) << 10) + lb16;
    char* dstT = lds + (size_t)uA * 1024 + lb16;

    auto issueA = [&](int gs) {
      char* dst = dstT + (size_t)(gs & 3) * 32768;
      const char* src = ((gs < 8) ? awT : auT) + (size_t)(gs & 7) * 8192;
      gload16(src, dst);
      gload16(src + 131072, dst + 16384);   // rt+2 (2 r-tiles x 64 kk x 1 KB)
    };
    // B: wave's 2 cols, kqs = step*8 + wk*2 + {0,1}
    const char* bw0 = (const char*)Wsp + (((size_t)(ct0 + wc * 2 + 0) * 64 + wk * 2) << 10) + lb16;
    const char* bw1 = (const char*)Wsp + (((size_t)(ct0 + wc * 2 + 1) * 64 + wk * 2) << 10) + lb16;
    const char* bu0 = (const char*)Usp + (((size_t)(ct0 + wc * 2 + 0) * 64 + wk * 2) << 10) + lb16;
    const char* bu1 = (const char*)Usp + (((size_t)(ct0 + wc * 2 + 1) * 64 + wk * 2) << 10) + lb16;

#define LOADB1(BN, GS)                                                        \
  do {                                                                        \
    const int gs_ = (GS);                                                     \
    size_t o_ = (size_t)(gs_ & 7) * 8192;                                     \
    const char* p0_ = ((gs_ < 8) ? bw0 : bu0) + o_;                           \
    const char* p1_ = ((gs_ < 8) ? bw1 : bu1) + o_;                           \
    asm volatile("global_load_dwordx4 %0, %1, off" : "=v"(BN.v[0][0]) : "v"(p0_));        \
    asm volatile("global_load_dwordx4 %0, %1, off" : "=v"(BN.v[0][1]) : "v"(p0_ + 1024)); \
    asm volatile("global_load_dwordx4 %0, %1, off" : "=v"(BN.v[1][0]) : "v"(p1_));        \
    asm volatile("global_load_dwordx4 %0, %1, off" : "=v"(BN.v[1][1]) : "v"(p1_ + 1024)); \
  } while (0)

    auto computeStep = [&](int g, const BF2& Bf) {
      const char* base = lds + (size_t)(g & 3) * 32768;
#pragma unroll
      for (int x = 0; x < 2; ++x) {
        bf16x8 av0 = *(const bf16x8*)(base + ((((wr * 2 + x) * 8 + wk * 2 + 0) << 10) + lb16));
        bf16x8 av1 = *(const bf16x8*)(base + ((((wr * 2 + x) * 8 + wk * 2 + 1) << 10) + lb16));
#pragma unroll
        for (int y = 0; y < 2; ++y) {
          acc[x][y] = MFMA(av0, Bf.v[y][0], acc[x][y]);
          acc[x][y] = MFMA(av1, Bf.v[y][1], acc[x][y]);
        }
      }
    };

    // ledger (per thread): prologue A0(2),B0(4),A1(2). STEP(g): issue
    // B(g+1)(4), A(g+2)(2) -> 14; leave newest 8 = {A(g+1)2,B(g+1)4,A(g+2)2}.
    // g=14: 12 outstanding, leave 6 = {A15:2,B15:4}; g=15: 0.
#define STEP1(G, BCUR, BNXT)                                         \
  do {                                                               \
    const int g_ = (G);                                              \
    if (g_ + 1 < 16) LOADB1(BNXT, g_ + 1);                           \
    if (g_ + 2 < 16) issueA(g_ + 2);                                 \
    if (g_ + 2 < 16) { WAITV(8); }                                   \
    else if (g_ + 1 < 16) { WAITV(6); }                              \
    else { WAITV(0); }                                               \
    __builtin_amdgcn_s_barrier();                                    \
    __builtin_amdgcn_sched_barrier(0);                               \
    computeStep(g_, BCUR);                                           \
    __builtin_amdgcn_sched_barrier(0);                               \
  } while (0)

    BF2 Bq0, Bq1;
    issueA(0); LOADB1(Bq0, 0); issueA(1);
    for (int g = 0; g < 16; g += 2) {
      STEP1(g, Bq0, Bq1);
      STEP1(g + 1, Bq1, Bq0);
    }
#undef STEP1
#undef LOADB1
  }

  // ---- K-split reduction: wk=1..3 -> LDS -> wk=0, fixed order ----
  const int wid = wr * 2 + wc;   // 0..3
  __syncthreads();
  if (wk != 0) {
    char* dst = lds + ((size_t)((wk - 1) * 4 + wid) << 12);
#pragma unroll
    for (int x = 0; x < 2; ++x)
#pragma unroll
      for (int y = 0; y < 2; ++y)
        *(f32x4*)(dst + ((((x * 2 + y) * 64) + lane) << 4)) = acc[x][y];
  }
  __syncthreads();
  if (wk != 0) return;
#pragma unroll
  for (int kq = 1; kq < 4; ++kq) {
    const char* srcp = lds + ((size_t)((kq - 1) * 4 + wid) << 12);
#pragma unroll
    for (int x = 0; x < 2; ++x)
#pragma unroll
      for (int y = 0; y < 2; ++y)
        acc[x][y] += *(const f32x4*)(srcp + ((((x * 2 + y) * 64) + lane) << 4));
  }

  // Epilogue: bias + tanh, store into A-pack layout of h_l (parity pw).
  // C/D layout: col = lane&15, row = (lane>>4)*4 + i.
  const float* bias = (l == 0) ? b0 : b1;
  short* H = hb(l, pw);
  const int lo = lane & 15, hi = lane >> 4;
  const int mb = (rb & 1) * 64 + wr * 32;
  const int nb = cb * 64 + wc * 32;
  const float bv0 = bias[nb + lo];
  const float bv1 = bias[nb + 16 + lo];
#pragma unroll
  for (int x = 0; x < 2; ++x)
#pragma unroll
    for (int y = 0; y < 2; ++y) {
      float bbv = y ? bv1 : bv0;
#pragma unroll
      for (int i = 0; i < 4; ++i) {
        int m = mb + x * 16 + hi * 4 + i;
        int n = nb + y * 16 + lo;
        float z = acc[x][y][i] + bbv;
        float e = __expf(2.f * z);
        float th = 1.f - 2.f / (e + 1.f);
        int r  = m >> 4, kk = n >> 5;
        int lp = (m & 15) | (((n >> 3) & 3) << 4);
        H[(((size_t)r * 64 + kk) * 64 + lp) * 8 + (n & 7)] = f2bf(th);
      }
    }
}

// ---------------------------------------------------------------------------
// Output head: out[b] = sigmoid(h3[b] . Wo + bo); h3 in A-pack layout.
// ---------------------------------------------------------------------------
__global__ __launch_bounds__(256) void head_kernel(
    const short* __restrict__ h3, const float* __restrict__ Wo,
    const float* __restrict__ bo, float* __restrict__ out) {
  __shared__ float sred[4];
  int b = blockIdx.x, tid = threadIdx.x;
  int kk = tid >> 2, hi = tid & 3;
  const bf16x8 v = *reinterpret_cast<const bf16x8*>(
      h3 + (((size_t)(b >> 4) * 64 + kk) * 64 + ((b & 15) | (hi << 4))) * 8);
  int k0 = kk * 32 + hi * 8;
  float acc = 0.f;
#pragma unroll
  for (int j = 0; j < 8; ++j) acc += bf2f(v[j]) * Wo[k0 + j];
  for (int off = 32; off > 0; off >>= 1) acc += __shfl_down(acc, off);
  if ((tid & 63) == 0) sred[tid >> 6] = acc;
  __syncthreads();
  if (tid == 0) {
    float z = sred[0] + sred[1] + sred[2] + sred[3] + bo[0];
    out[b] = 1.f / (1.f + expf(-z));
  }
}

extern "C" void kernel_launch(void* const* d_in, const int* in_sizes, int n_in,
                              void* d_out, int out_size, void* d_ws, size_t ws_size,
                              hipStream_t stream) {
  const int*   tokens = (const int*)d_in[0];
  const float* emb    = (const float*)d_in[1];
  const float* W0     = (const float*)d_in[2];
  const float* U0     = (const float*)d_in[3];
  const float* b0     = (const float*)d_in[4];
  const float* W1     = (const float*)d_in[5];
  const float* U1     = (const float*)d_in[6];
  const float* b1     = (const float*)d_in[7];
  const float* Wo     = (const float*)d_in[8];
  const float* bo     = (const float*)d_in[9];
  float* out = (float*)d_out;
  short* ws  = (short*)d_ws;

  const size_t W0P_SZ = (size_t)128 * 4 * 512;     // 262144
  const size_t UP_SZ  = (size_t)128 * 64 * 512;    // 4194304
  const size_t EP_SZ  = (size_t)SEQ * 16384;       // 1310720
  const size_t H_SZ   = (size_t)8 * 64 * 64 * 8;   // 262144 per buffer

  short* W0p = ws;
  short* U0p = W0p + W0P_SZ;
  short* W1p = U0p + UP_SZ;
  short* U1p = W1p + UP_SZ;
  short* Ep  = U1p + UP_SZ;
  short* hbase = Ep + EP_SZ;

  {
    int unitsW0 = (UNITS / 16) * (EPAD / 32);   // 512
    pack_b_kernel<<<(unitsW0 + 3) / 4, 256, 0, stream>>>(W0, EMB, UNITS, EPAD / 32, unitsW0, W0p);
    int unitsU = (UNITS / 16) * (UNITS / 32);   // 8192
    pack_b_kernel<<<(unitsU + 3) / 4, 256, 0, stream>>>(U0, UNITS, UNITS, UNITS / 32, unitsU, U0p);
    pack_b_kernel<<<(unitsU + 3) / 4, 256, 0, stream>>>(W1, UNITS, UNITS, UNITS / 32, unitsU, W1p);
    pack_b_kernel<<<(unitsU + 3) / 4, 256, 0, stream>>>(U1, UNITS, UNITS, UNITS / 32, unitsU, U1p);
    int ne = SEQ * 8 * 4 * 64;
    pack_e_kernel<<<(ne + 255) / 256, 256, 0, stream>>>(tokens, emb, Ep);
  }

  // zero all 8 h double-buffers (provides h_l[-1] = 0)
  hipMemsetAsync(hbase, 0, 8u * H_SZ * 2u, stream);

  // ---- 83 diagonals: s = t + l ----
  for (int s = 0; s <= SEQ - 1 + 3; ++s) {
    diag_kernel<<<256, 1024, 0, stream>>>(Ep, W0p, U0p, W1p, U1p, b0, b1, hbase, s);
  }

  // final head: h3[SEQ-1] written at diagonal 82 (parity 0)
  head_kernel<<<BATCH, 256, 0, stream>>>(hbase + 6 * H_SZ, Wo, bo, out);
}